// Round 2
// baseline (1710.335 us; speedup 1.0000x reference)
//
#include <hip/hip_runtime.h>
#include <hip/hip_bf16.h>
#include <math.h>

#define TTOK 4096
#define HD   1536
#define IDIM 768
#define NE   64
#define KSEL 8
#define CAP  1024
#define ECAP (NE * CAP)

typedef unsigned int uint32;
typedef __bf16 bf16;
typedef __attribute__((ext_vector_type(8))) __bf16 bf16x8;
typedef __attribute__((ext_vector_type(4))) __bf16 bf16x4;
typedef __attribute__((ext_vector_type(4))) float f32x4;

// async global->LDS, 16B per lane, dest = wave-uniform base + lane*16
#define GLD16(g, l) __builtin_amdgcn_global_load_lds( \
    (const __attribute__((address_space(1))) void*)(g), \
    (__attribute__((address_space(3))) void*)(l), 16, 0, 0)

// ---------------------------------------------------------------- cast fp32 -> bf16 (weights + x, one grid)
// wg/wu/wd: 75,497,472 elems each -> 36864 blocks each; x: 6,291,456 -> 3072 blocks
__global__ __launch_bounds__(256) void k_castall(const float* __restrict__ wg, const float* __restrict__ wu,
        const float* __restrict__ wd, const float* __restrict__ x,
        bf16* __restrict__ wgb, bf16* __restrict__ wub, bf16* __restrict__ wdb, bf16* __restrict__ xb) {
    int b = blockIdx.x;
    const float* src; bf16* dst; int base;
    if      (b <  36864) { src = wg; dst = wgb; base = b; }
    else if (b <  73728) { src = wu; dst = wub; base = b - 36864; }
    else if (b < 110592) { src = wd; dst = wdb; base = b - 73728; }
    else                 { src = x;  dst = xb;  base = b - 110592; }
    size_t i = ((size_t)base * 256 + threadIdx.x) * 8;
    float4 a = *(const float4*)(src + i);
    float4 c = *(const float4*)(src + i + 4);
    bf16x8 o;
    o[0] = (bf16)a.x; o[1] = (bf16)a.y; o[2] = (bf16)a.z; o[3] = (bf16)a.w;
    o[4] = (bf16)c.x; o[5] = (bf16)c.y; o[6] = (bf16)c.z; o[7] = (bf16)c.w;
    *(bf16x8*)(dst + i) = o;
}

// ---------------------------------------------------------------- router logits (fp64 accumulate)
__global__ __launch_bounds__(256) void k_router(const float* __restrict__ x, const float* __restrict__ gw,
                                                double* __restrict__ logits) {
    __shared__ float Xt[8 * HD];   // 48 KB
    int t0 = blockIdx.x * 8;
    int tid = threadIdx.x;
    {
        const float4* src = (const float4*)(x + (size_t)t0 * HD);
        float4* dst = (float4*)Xt;
        for (int u = tid; u < 8 * HD / 4; u += 256) dst[u] = src[u];
    }
    __syncthreads();
    int tr = tid >> 5;
    int er = (tid & 31) * 2;
    const float* xr = Xt + tr * HD;
    const float* g0 = gw + (size_t)er * HD;
    const float* g1 = g0 + HD;
    double c0 = 0.0, c1 = 0.0;
    for (int k = 0; k < HD; k += 4) {
        float4 a  = *(const float4*)(xr + k);
        float4 b0 = *(const float4*)(g0 + k);
        float4 b1 = *(const float4*)(g1 + k);
        c0 += (double)a.x * b0.x + (double)a.y * b0.y + (double)a.z * b0.z + (double)a.w * b0.w;
        c1 += (double)a.x * b1.x + (double)a.y * b1.y + (double)a.z * b1.z + (double)a.w * b1.w;
    }
    double* lp = logits + (size_t)(t0 + tr) * NE + er;
    lp[0] = c0; lp[1] = c1;
}

// ---------------------------------------------------------------- top-8 + slot assignment
__global__ __launch_bounds__(64) void k_topk(const double* __restrict__ logits, const float* __restrict__ bias,
                                             float* __restrict__ wv, uint32* __restrict__ rowtok,
                                             uint32* __restrict__ tkof, int* __restrict__ cnt) {
    int t = blockIdx.x, lane = threadIdx.x;
    double lg = logits[(size_t)t * NE + lane];
    double sig = 1.0 / (1.0 + exp(-lg));
    double sel = sig + (double)bias[lane];
    double mysig = sig;
    double wsum = 0.0;
    int my_e = -1; double my_s = 0.0;
    for (int k = 0; k < KSEL; ++k) {
        double v = sel; int ei = lane;
        #pragma unroll
        for (int off = 32; off > 0; off >>= 1) {
            double ov = __shfl_down(v, off);
            int    oi = __shfl_down(ei, off);
            if (ov > v || (ov == v && oi < ei)) { v = ov; ei = oi; }
        }
        ei = __shfl(ei, 0);
        double sw = __shfl(mysig, ei);
        wsum += sw;
        if (lane == k) { my_e = ei; my_s = sw; }
        if (lane == ei) sel = -1.0e300;
    }
    if (lane < KSEL) {
        float w = (float)(my_s / wsum);
        int tk = t * KSEL + lane;
        int pos = atomicAdd(cnt + my_e, 1);
        if (pos < CAP) {
            rowtok[my_e * CAP + pos] = (uint32)t;
            tkof  [my_e * CAP + pos] = (uint32)tk;
            wv[tk] = w;
        } else {
            wv[tk] = 0.0f;
        }
    }
}

// ---------------------------------------------------------------- gemm1: Hc = silu(x@Wg^T) * (x@Wu^T)
// m97-style: global_load_lds staging, LDS [group16][kc][mr][8elem], 16 MFMA : 8 ds_read_b128 per wave-step
__global__ __launch_bounds__(256) void k_gemm1(const bf16* __restrict__ xb,
        const bf16* __restrict__ wgb, const bf16* __restrict__ wub,
        const uint32* __restrict__ rowtok, const int* __restrict__ cnt,
        bf16* __restrict__ hc) {
    int id = blockIdx.x;
    int G  = ((id >> 6) << 3) | (id & 7);   // e*12+nt; same (e,nt) m-tiles share an XCD
    int mt = (id >> 3) & 7;
    int e  = G / 12, nt = G % 12;
    int n_rows = cnt[e];
    if (mt * 128 >= n_rows) return;

    __shared__ __align__(16) bf16 As[128 * 32];  // 8KB: [g8][kc4][mr16][8]
    __shared__ __align__(16) bf16 Bg[64 * 32];   // 4KB: [g4][kc4][nr16][8]
    __shared__ __align__(16) bf16 Bu[64 * 32];

    int tid = threadIdx.x, wave = tid >> 6, lane = tid & 63;
    int kc = lane >> 4, mr = lane & 15;

    int g0 = wave * 2, g1 = g0 + 1;
    int r0 = mt * 128 + g0 * 16 + mr, r1 = mt * 128 + g1 * 16 + mr;
    uint32 tok0 = (r0 < n_rows) ? rowtok[e * CAP + r0] : 0u;
    uint32 tok1 = (r1 < n_rows) ? rowtok[e * CAP + r1] : 0u;
    const bf16* ga0 = xb + (size_t)tok0 * HD + kc * 8;
    const bf16* ga1 = xb + (size_t)tok1 * HD + kc * 8;
    const bf16* gbg = wgb + ((size_t)e * IDIM + nt * 64 + wave * 16 + mr) * HD + kc * 8;
    const bf16* gbu = wub + ((size_t)e * IDIM + nt * 64 + wave * 16 + mr) * HD + kc * 8;

    bf16* lA0 = As + g0 * 512;
    bf16* lA1 = As + g1 * 512;
    bf16* lBg = Bg + wave * 512;
    bf16* lBu = Bu + wave * 512;

    int wm = wave & 1, wn = wave >> 1;
    int r = lane & 15, q = lane >> 4;

    f32x4 zero = {0.f, 0.f, 0.f, 0.f};
    f32x4 accg[4][2], accu[4][2];
    #pragma unroll
    for (int s = 0; s < 4; ++s)
        #pragma unroll
        for (int t2 = 0; t2 < 2; ++t2) { accg[s][t2] = zero; accu[s][t2] = zero; }

    for (int k0 = 0; k0 < HD; k0 += 32) {
        GLD16(ga0 + k0, lA0);
        GLD16(ga1 + k0, lA1);
        GLD16(gbg + k0, lBg);
        GLD16(gbu + k0, lBu);
        __syncthreads();   // drains vmcnt(0): DMA complete, all waves see tile
        bf16x8 af[4], bgf[2], buf2[2];
        #pragma unroll
        for (int s = 0; s < 4; ++s)
            af[s] = *(const bf16x8*)(As + (wm * 4 + s) * 512 + lane * 8);
        #pragma unroll
        for (int t2 = 0; t2 < 2; ++t2) {
            bgf[t2]  = *(const bf16x8*)(Bg + (wn * 2 + t2) * 512 + lane * 8);
            buf2[t2] = *(const bf16x8*)(Bu + (wn * 2 + t2) * 512 + lane * 8);
        }
        #pragma unroll
        for (int s = 0; s < 4; ++s)
            #pragma unroll
            for (int t2 = 0; t2 < 2; ++t2) {
                accg[s][t2] = __builtin_amdgcn_mfma_f32_16x16x32_bf16(af[s], bgf[t2],  accg[s][t2], 0, 0, 0);
                accu[s][t2] = __builtin_amdgcn_mfma_f32_16x16x32_bf16(af[s], buf2[t2], accu[s][t2], 0, 0, 0);
            }
        __syncthreads();   // readers done before next DMA overwrites
    }
    size_t rowbase = (size_t)e * CAP + mt * 128;
    #pragma unroll
    for (int s = 0; s < 4; ++s)
        #pragma unroll
        for (int t2 = 0; t2 < 2; ++t2)
            #pragma unroll
            for (int rg = 0; rg < 4; ++rg) {
                int row = wm * 64 + s * 16 + q * 4 + rg;
                int col = nt * 64 + wn * 32 + t2 * 16 + r;
                float g = accg[s][t2][rg], u = accu[s][t2][rg];
                float h = g / (1.f + __expf(-g)) * u;
                hc[(rowbase + row) * (size_t)IDIM + col] = (bf16)h;
            }
}

// ---------------------------------------------------------------- gemm2: Yw[tk] = Hc @ Wd^T (scatter rows)
__global__ __launch_bounds__(256) void k_gemm2(const bf16* __restrict__ hc,
        const bf16* __restrict__ wdb, const uint32* __restrict__ tkof,
        const int* __restrict__ cnt, bf16* __restrict__ yw) {
    int id = blockIdx.x;
    int G  = ((id >> 6) << 3) | (id & 7);
    int mt = (id >> 3) & 7;
    int e  = G / 12, nt = G % 12;
    int n_rows = cnt[e];
    if (mt * 128 >= n_rows) return;

    __shared__ __align__(16) bf16 As[128 * 32];  // 8KB
    __shared__ __align__(16) bf16 Bs[128 * 32];  // 8KB

    int tid = threadIdx.x, wave = tid >> 6, lane = tid & 63;
    int kc = lane >> 4, mr = lane & 15;

    int g0 = wave * 2, g1 = g0 + 1;
    const bf16* ga0 = hc + ((size_t)e * CAP + mt * 128 + g0 * 16 + mr) * IDIM + kc * 8;
    const bf16* ga1 = hc + ((size_t)e * CAP + mt * 128 + g1 * 16 + mr) * IDIM + kc * 8;
    const bf16* gb0 = wdb + ((size_t)e * HD + nt * 128 + g0 * 16 + mr) * IDIM + kc * 8;
    const bf16* gb1 = wdb + ((size_t)e * HD + nt * 128 + g1 * 16 + mr) * IDIM + kc * 8;

    bf16* lA0 = As + g0 * 512;
    bf16* lA1 = As + g1 * 512;
    bf16* lB0 = Bs + g0 * 512;
    bf16* lB1 = Bs + g1 * 512;

    int wm = wave & 1, wn = wave >> 1;
    int r = lane & 15, q = lane >> 4;

    f32x4 zero = {0.f, 0.f, 0.f, 0.f};
    f32x4 acc[4][4];
    #pragma unroll
    for (int s = 0; s < 4; ++s)
        #pragma unroll
        for (int t2 = 0; t2 < 4; ++t2) acc[s][t2] = zero;

    for (int k0 = 0; k0 < IDIM; k0 += 32) {
        GLD16(ga0 + k0, lA0);
        GLD16(ga1 + k0, lA1);
        GLD16(gb0 + k0, lB0);
        GLD16(gb1 + k0, lB1);
        __syncthreads();
        bf16x8 af[4], bf4[4];
        #pragma unroll
        for (int s = 0; s < 4; ++s)
            af[s] = *(const bf16x8*)(As + (wm * 4 + s) * 512 + lane * 8);
        #pragma unroll
        for (int t2 = 0; t2 < 4; ++t2)
            bf4[t2] = *(const bf16x8*)(Bs + (wn * 4 + t2) * 512 + lane * 8);
        #pragma unroll
        for (int s = 0; s < 4; ++s)
            #pragma unroll
            for (int t2 = 0; t2 < 4; ++t2)
                acc[s][t2] = __builtin_amdgcn_mfma_f32_16x16x32_bf16(af[s], bf4[t2], acc[s][t2], 0, 0, 0);
        __syncthreads();
    }
    uint32 tkx[4][4];
    #pragma unroll
    for (int s = 0; s < 4; ++s)
        #pragma unroll
        for (int rg = 0; rg < 4; ++rg) {
            int row = mt * 128 + wm * 64 + s * 16 + q * 4 + rg;
            tkx[s][rg] = (row < n_rows) ? tkof[e * CAP + row] : 0xFFFFFFFFu;
        }
    #pragma unroll
    for (int s = 0; s < 4; ++s)
        #pragma unroll
        for (int t2 = 0; t2 < 4; ++t2)
            #pragma unroll
            for (int rg = 0; rg < 4; ++rg) {
                if (tkx[s][rg] != 0xFFFFFFFFu) {
                    int col = nt * 128 + wn * 64 + t2 * 16 + r;
                    yw[(size_t)tkx[s][rg] * HD + col] = (bf16)acc[s][t2][rg];
                }
            }
}

// ---------------------------------------------------------------- combine: out[t] = sum_k w_k * Yw[t,k]
__global__ __launch_bounds__(256) void k_combine(const bf16* __restrict__ yw,
        const float* __restrict__ wv, float* __restrict__ out) {
    int t = blockIdx.x, tid = threadIdx.x;
    __shared__ float w8[KSEL];
    if (tid < KSEL) w8[tid] = wv[t * KSEL + tid];
    __syncthreads();
    for (int c0 = tid * 4; c0 < HD; c0 += 1024) {
        float a0 = 0.f, a1 = 0.f, a2 = 0.f, a3 = 0.f;
        #pragma unroll
        for (int k = 0; k < KSEL; ++k) {
            bf16x4 v = *(const bf16x4*)(yw + ((size_t)(t * KSEL + k)) * HD + c0);
            float wk = w8[k];
            a0 += wk * (float)v[0];
            a1 += wk * (float)v[1];
            a2 += wk * (float)v[2];
            a3 += wk * (float)v[3];
        }
        float4 o = {a0, a1, a2, a3};
        *(float4*)(out + (size_t)t * HD + c0) = o;
    }
}

// ---------------------------------------------------------------- launch
extern "C" void kernel_launch(void* const* d_in, const int* in_sizes, int n_in,
                              void* d_out, int out_size, void* d_ws, size_t ws_size,
                              hipStream_t stream) {
    const float* x  = (const float*)d_in[0];
    const float* gw = (const float*)d_in[1];
    const float* rb = (const float*)d_in[2];
    const float* wg = (const float*)d_in[3];
    const float* wu = (const float*)d_in[4];
    const float* wd = (const float*)d_in[5];
    float* out = (float*)d_out;

    char* ws = (char*)d_ws;
    size_t off = 0;
    auto alloc = [&](size_t bytes) -> void* {
        off = (off + 255) & ~(size_t)255;
        void* p = ws + off;
        off += bytes;
        return p;
    };
    const size_t WELEM = (size_t)NE * IDIM * HD;                     // 75,497,472
    bf16*   xb     = (bf16*)   alloc((size_t)TTOK * HD * 2);        // 12.6 MB
    double* logits = (double*) alloc((size_t)TTOK * NE * 8);        //  2.1 MB
    float*  wv     = (float*)  alloc((size_t)TTOK * KSEL * 4);
    uint32* rowtok = (uint32*) alloc((size_t)ECAP * 4);
    uint32* tkof   = (uint32*) alloc((size_t)ECAP * 4);
    int*    cnt    = (int*)    alloc(256);
    bf16*   wdb    = (bf16*)   alloc(WELEM * 2);                    // 151 MB
    bf16*   hc     = (bf16*)   alloc((size_t)ECAP * IDIM * 2);      // 100.7 MB
    bf16*   wgb    = (bf16*)   alloc(WELEM * 2);                    // 151 MB  (aliased by yw after gemm1)
    bf16*   wub    = (bf16*)   alloc(WELEM * 2);                    // 151 MB
    bf16*   yw     = wgb;      // wgb/wub dead after gemm1; yw needs 100.7 MB <= 302 MB
    (void)ws_size; (void)in_sizes; (void)n_in; (void)out_size;

    hipMemsetAsync(cnt, 0, 256, stream);
    k_castall<<<113664,   256, 0, stream>>>(wg, wu, wd, x, wgb, wub, wdb, xb);
    k_router <<<TTOK / 8, 256, 0, stream>>>(x, gw, logits);
    k_topk   <<<TTOK,     64,  0, stream>>>(logits, rb, wv, rowtok, tkof, cnt);
    k_gemm1  <<<6144,     256, 0, stream>>>(xb, wgb, wub, rowtok, cnt, hc);
    k_gemm2  <<<6144,     256, 0, stream>>>(hc, wdb, tkof, cnt, yw);
    k_combine<<<TTOK,     256, 0, stream>>>(yw, wv, out);
}